// Round 6
// baseline (484.159 us; speedup 1.0000x reference)
//
#include <hip/hip_runtime.h>
#include <hip/hip_bf16.h>

#define NFEAT 128

typedef __attribute__((ext_vector_type(8))) short short8;
typedef __attribute__((ext_vector_type(4))) float float4v;

__device__ inline short f32_bf16(float f) {
  unsigned u = __builtin_bit_cast(unsigned, f);
  unsigned r = (u + 0x7fffu + ((u >> 16) & 1u)) >> 16;
  return (short)r;
}
__device__ inline float bf16_f32(unsigned short s) {
  return __builtin_bit_cast(float, (unsigned)s << 16);
}

// ---------------------------------------------------------------------------
// Repack W (fp32, KxCOLS row-major) into B-fragment order for
// mfma_f32_16x16x32_bf16.
// ---------------------------------------------------------------------------
__device__ inline void repack_one(const float* __restrict__ W,
                                  short* __restrict__ Wf, int COLS) {
  int nfrag = (COLS / 16) * 4 * 64;
  for (int f = threadIdx.x; f < nfrag; f += 256) {
    int lane = f & 63, c = (f >> 6) & 3, t = f >> 8;
    int k0 = c * 32 + (lane >> 4) * 8;
    int n = t * 16 + (lane & 15);
    short8 v;
#pragma unroll
    for (int j = 0; j < 8; j++) v[j] = f32_bf16(W[(size_t)(k0 + j) * COLS + n]);
    *(short8*)&Wf[(size_t)f * 8] = v;
  }
}
__global__ __launch_bounds__(256) void repack_w_kernel(
    const float* __restrict__ W1, short* __restrict__ W1f,
    const float* __restrict__ W2, short* __restrict__ W2f) {
  if (blockIdx.x == 0) repack_one(W1, W1f, 128);
  else repack_one(W2, W2f, 64);
}

// ---------------------------------------------------------------------------
// MFMA GEMM: Y_bf16[nrows x COLS] = A[nrows x 128] @ W[128 x COLS]
// ---------------------------------------------------------------------------
template <int COLS, bool IN_BF16>
__global__ __launch_bounds__(256) void gemm_mfma(
    const void* __restrict__ Av, const short* __restrict__ Wf,
    short* __restrict__ Y, int nrows) {
  constexpr int NT = COLS / 16;
  __shared__ __align__(16) short lds[COLS * 128];

  {
    const int4* s = (const int4*)Wf;
    int4* d = (int4*)lds;
    for (int i = threadIdx.x; i < COLS * 16; i += 256) d[i] = s[i];
  }
  __syncthreads();

  const int wave = threadIdx.x >> 6;
  const int lane = threadIdx.x & 63;
  const int m = lane & 15;
  const int q = lane >> 4;
  const int rowA = blockIdx.x * 64 + wave * 16 + m;

  float4v acc[NT];
#pragma unroll
  for (int t = 0; t < NT; t++) acc[t] = (float4v){0.f, 0.f, 0.f, 0.f};

  const short8* ldsf = (const short8*)lds;
#pragma unroll
  for (int c = 0; c < 4; c++) {
    short8 a = (short8){0, 0, 0, 0, 0, 0, 0, 0};
    if (rowA < nrows) {
      if constexpr (IN_BF16) {
        a = *(const short8*)((const short*)Av + (size_t)rowA * 128 + c * 32 + q * 8);
      } else {
        const float* xp = (const float*)Av + (size_t)rowA * 128 + c * 32 + q * 8;
        float4 x0 = *(const float4*)xp;
        float4 x1 = *(const float4*)(xp + 4);
        a[0] = f32_bf16(x0.x); a[1] = f32_bf16(x0.y);
        a[2] = f32_bf16(x0.z); a[3] = f32_bf16(x0.w);
        a[4] = f32_bf16(x1.x); a[5] = f32_bf16(x1.y);
        a[6] = f32_bf16(x1.z); a[7] = f32_bf16(x1.w);
      }
    }
#pragma unroll
    for (int t = 0; t < NT; t++) {
      acc[t] = __builtin_amdgcn_mfma_f32_16x16x32_bf16(
          a, ldsf[(t * 4 + c) * 64 + lane], acc[t], 0, 0, 0);
    }
  }

  const int rbase = blockIdx.x * 64 + wave * 16 + q * 4;
#pragma unroll
  for (int t = 0; t < NT; t++) {
#pragma unroll
    for (int r = 0; r < 4; r++) {
      int rr = rbase + r;
      if (rr < nrows) Y[(size_t)rr * COLS + t * 16 + m] = f32_bf16(acc[t][r]);
    }
  }
}

// ---------------------------------------------------------------------------
// CSR build
// ---------------------------------------------------------------------------
__global__ __launch_bounds__(256) void hist_kernel(
    const int* __restrict__ dst, int* __restrict__ cnt, int E) {
  int e = blockIdx.x * 256 + threadIdx.x;
  if (e < E) atomicAdd(&cnt[dst[e]], 1);
}

#define SCAN_TILE 1024

__global__ __launch_bounds__(256) void scan_phase1(
    const int* __restrict__ cnt, int* __restrict__ partials, int N) {
  const int tid = threadIdx.x;
  const int base = blockIdx.x * SCAN_TILE + tid * 4;
  int s = 0;
  if (base + 3 < N) {
    int4 v = *(const int4*)&cnt[base];
    s = v.x + v.y + v.z + v.w;
  } else {
    for (int k = 0; k < 4; k++)
      if (base + k < N) s += cnt[base + k];
  }
  for (int off = 32; off > 0; off >>= 1) s += __shfl_down(s, off);
  __shared__ int ws[4];
  if ((tid & 63) == 0) ws[tid >> 6] = s;
  __syncthreads();
  if (tid == 0) partials[blockIdx.x] = ws[0] + ws[1] + ws[2] + ws[3];
}

__global__ __launch_bounds__(1024) void scan_phase2(
    int* __restrict__ partials, int nb) {
  __shared__ int sh[1024];
  const int t = threadIdx.x;
  sh[t] = (t < nb) ? partials[t] : 0;
  __syncthreads();
  for (int off = 1; off < 1024; off <<= 1) {
    int other = (t >= off) ? sh[t - off] : 0;
    __syncthreads();
    sh[t] += other;
    __syncthreads();
  }
  if (t < nb) partials[t] = (t > 0) ? sh[t - 1] : 0;
}

__global__ __launch_bounds__(256) void scan_phase3(
    const int* __restrict__ cnt, const int* __restrict__ partials,
    int* __restrict__ offsets, int N, int E) {
  const int tid = threadIdx.x;
  const int base = blockIdx.x * SCAN_TILE + tid * 4;
  int v0 = 0, v1 = 0, v2 = 0, v3 = 0;
  if (base + 3 < N) {
    int4 v = *(const int4*)&cnt[base];
    v0 = v.x; v1 = v.y; v2 = v.z; v3 = v.w;
  } else {
    if (base + 0 < N) v0 = cnt[base + 0];
    if (base + 1 < N) v1 = cnt[base + 1];
    if (base + 2 < N) v2 = cnt[base + 2];
    if (base + 3 < N) v3 = cnt[base + 3];
  }
  int mysum = v0 + v1 + v2 + v3;
  __shared__ int sh[256];
  sh[tid] = mysum;
  __syncthreads();
  for (int off = 1; off < 256; off <<= 1) {
    int other = (tid >= off) ? sh[tid - off] : 0;
    __syncthreads();
    sh[tid] += other;
    __syncthreads();
  }
  int run = partials[blockIdx.x] + ((tid > 0) ? sh[tid - 1] : 0);
  if (base + 3 < N) {
    int4 o;
    o.x = run;
    o.y = run + v0;
    o.z = run + v0 + v1;
    o.w = run + v0 + v1 + v2;
    *(int4*)&offsets[base] = o;
  } else {
    int r = run;
    if (base + 0 < N) { offsets[base + 0] = r; r += v0; }
    if (base + 1 < N) { offsets[base + 1] = r; r += v1; }
    if (base + 2 < N) { offsets[base + 2] = r; r += v2; }
    if (base + 3 < N) { offsets[base + 3] = r; r += v3; }
  }
  if (blockIdx.x == 0 && tid == 0) offsets[N] = E;
}

// ---------------------------------------------------------------------------
// XCD-affine fill with work-stealing.
// Window w covers nodes [w*win, (w+1)*win). Blocks prefer the window matching
// their *physical* XCD (HW_REG_XCC_ID), so the window's csr_src region is
// dirtied by exactly one XCD's L2 and lines evict full. Per-window atomic
// ticket queues guarantee every chunk is processed exactly once regardless of
// what XCC_ID returns -> correctness never depends on the mapping.
// ---------------------------------------------------------------------------
#define FILL_CHUNK 4096

__global__ __launch_bounds__(256) void fill_steal_kernel(
    const int* __restrict__ src, const int* __restrict__ dst,
    const int* __restrict__ offsets, int* __restrict__ cursor,
    int* __restrict__ csr_src, int* __restrict__ tickets,
    int E, int win_size) {
  unsigned xcc;
  asm volatile("s_getreg_b32 %0, hwreg(HW_REG_XCC_ID)" : "=s"(xcc));
  xcc &= 7;
  const int nchunks = (E + FILL_CHUNK - 1) / FILL_CHUNK;
  const int tid = threadIdx.x;
  __shared__ int sticket;

  for (int wi = 0; wi < 8; wi++) {
    const int w = (xcc + wi) & 7;
    const int lo = w * win_size;
    const int hi = lo + win_size;
    while (true) {
      if (tid == 0) sticket = atomicAdd(&tickets[w], 1);
      __syncthreads();
      const int t = sticket;
      __syncthreads();
      if (t >= nchunks) break;
      const int base = t * FILL_CHUNK;
      const int end = min(E, base + FILL_CHUNK);
      // 4096 edges / 256 threads = 16 per thread; int4-vectorized dst scan
      for (int e4 = base + tid * 4; e4 < end; e4 += 256 * 4) {
        int4 d4;
        if (e4 + 3 < end) {
          d4 = *(const int4*)&dst[e4];
        } else {
          d4.x = dst[e4];
          d4.y = (e4 + 1 < end) ? dst[e4 + 1] : -1;
          d4.z = (e4 + 2 < end) ? dst[e4 + 2] : -1;
          d4.w = (e4 + 3 < end) ? dst[e4 + 3] : -1;
        }
#pragma unroll
        for (int k = 0; k < 4; k++) {
          int d = (k == 0) ? d4.x : (k == 1) ? d4.y : (k == 2) ? d4.z : d4.w;
          if (d >= lo && d < hi) {
            int p = atomicSub(&cursor[d], 1) - 1;
            csr_src[offsets[d] + p] = src[e4 + k];
          }
        }
      }
    }
  }
}

// ---------------------------------------------------------------------------
// Aggregations (one wave per node, fp32 accumulate, 4-way unrolled gather)
// ---------------------------------------------------------------------------
__global__ __launch_bounds__(256) void agg1_kernel(
    const short* __restrict__ Y, const int* __restrict__ csr_src,
    const int* __restrict__ offsets, const float* __restrict__ bias,
    short* __restrict__ H, int N) {
  const int node = (blockIdx.x * 256 + threadIdx.x) >> 6;
  const int lane = threadIdx.x & 63;
  if (node >= N) return;
  const int start = offsets[node];
  const int end = offsets[node + 1];
  float a0 = bias[2 * lane], a1 = bias[2 * lane + 1];
  for (int base = start; base < end; base += 64) {
    int my = (base + lane < end) ? csr_src[base + lane] : 0;
    int mcnt = min(64, end - base);
    int j = 0;
    for (; j + 4 <= mcnt; j += 4) {
      int s0 = __shfl(my, j + 0);
      int s1 = __shfl(my, j + 1);
      int s2 = __shfl(my, j + 2);
      int s3 = __shfl(my, j + 3);
      unsigned v0 = *(const unsigned*)&Y[(size_t)s0 * 128 + 2 * lane];
      unsigned v1 = *(const unsigned*)&Y[(size_t)s1 * 128 + 2 * lane];
      unsigned v2 = *(const unsigned*)&Y[(size_t)s2 * 128 + 2 * lane];
      unsigned v3 = *(const unsigned*)&Y[(size_t)s3 * 128 + 2 * lane];
      a0 += __builtin_bit_cast(float, v0 << 16);
      a1 += __builtin_bit_cast(float, v0 & 0xffff0000u);
      a0 += __builtin_bit_cast(float, v1 << 16);
      a1 += __builtin_bit_cast(float, v1 & 0xffff0000u);
      a0 += __builtin_bit_cast(float, v2 << 16);
      a1 += __builtin_bit_cast(float, v2 & 0xffff0000u);
      a0 += __builtin_bit_cast(float, v3 << 16);
      a1 += __builtin_bit_cast(float, v3 & 0xffff0000u);
    }
    for (; j < mcnt; j++) {
      int s = __shfl(my, j);
      unsigned v = *(const unsigned*)&Y[(size_t)s * 128 + 2 * lane];
      a0 += __builtin_bit_cast(float, v << 16);
      a1 += __builtin_bit_cast(float, v & 0xffff0000u);
    }
  }
  a0 = fmaxf(a0, 0.f);
  a1 = fmaxf(a1, 0.f);
  unsigned outv = (unsigned)(unsigned short)f32_bf16(a0) |
                  ((unsigned)(unsigned short)f32_bf16(a1) << 16);
  *(unsigned*)&H[(size_t)node * 128 + 2 * lane] = outv;
}

__global__ __launch_bounds__(256) void agg2_kernel(
    const short* __restrict__ Y, const int* __restrict__ csr_src,
    const int* __restrict__ offsets, const float* __restrict__ bias,
    float* __restrict__ out, int N) {
  const int node = (blockIdx.x * 256 + threadIdx.x) >> 6;
  const int lane = threadIdx.x & 63;
  if (node >= N) return;
  const int start = offsets[node];
  const int end = offsets[node + 1];
  float acc = bias[lane];
  for (int base = start; base < end; base += 64) {
    int my = (base + lane < end) ? csr_src[base + lane] : 0;
    int mcnt = min(64, end - base);
    int j = 0;
    for (; j + 4 <= mcnt; j += 4) {
      int s0 = __shfl(my, j + 0);
      int s1 = __shfl(my, j + 1);
      int s2 = __shfl(my, j + 2);
      int s3 = __shfl(my, j + 3);
      unsigned short w0 = *(const unsigned short*)&Y[(size_t)s0 * 64 + lane];
      unsigned short w1 = *(const unsigned short*)&Y[(size_t)s1 * 64 + lane];
      unsigned short w2 = *(const unsigned short*)&Y[(size_t)s2 * 64 + lane];
      unsigned short w3 = *(const unsigned short*)&Y[(size_t)s3 * 64 + lane];
      acc += bf16_f32(w0) + bf16_f32(w1) + bf16_f32(w2) + bf16_f32(w3);
    }
    for (; j < mcnt; j++) {
      int s = __shfl(my, j);
      acc += bf16_f32(*(const unsigned short*)&Y[(size_t)s * 64 + lane]);
    }
  }
  out[(size_t)node * 64 + lane] = acc;
}

extern "C" void kernel_launch(void* const* d_in, const int* in_sizes, int n_in,
                              void* d_out, int out_size, void* d_ws, size_t ws_size,
                              hipStream_t stream) {
  const float* x  = (const float*)d_in[0];
  const int* src  = (const int*)d_in[1];
  const int* dst  = (const int*)d_in[2];
  const float* W1 = (const float*)d_in[3];
  const float* b1 = (const float*)d_in[4];
  const float* W2 = (const float*)d_in[5];
  const float* b2 = (const float*)d_in[6];
  float* out = (float*)d_out;

  const int N = in_sizes[0] / NFEAT;   // 100000
  const int E = in_sizes[1];           // 1600000

  // workspace layout
  short* y1  = (short*)d_ws;                       // N*128 bf16
  short* h   = y1 + (size_t)N * 128;               // N*128 bf16
  short* y2  = h + (size_t)N * 128;                // N*64 bf16
  short* w1f = y2 + (size_t)N * 64;                // 128*128 bf16
  short* w2f = w1f + 128 * 128;                    // 128*64 bf16
  int* counts = (int*)(((uintptr_t)(w2f + 128 * 64) + 15) & ~(uintptr_t)15);
  int* offsets  = counts + N;                      // N+1
  int* csr_src  = offsets + N + 1;                 // E
  int* partials = csr_src + E;                     // <=1024
  int* tickets  = partials + 1024;                 // 8

  const int edge_blocks = (E + 255) / 256;
  const int scan_blocks = (N + SCAN_TILE - 1) / SCAN_TILE;
  const int gemm_blocks = (N + 63) / 64;
  const int agg_blocks = (N * 64 + 255) / 256;
  const int win_size = (N + 7) / 8;

  // ---- weight repack ----
  repack_w_kernel<<<2, 256, 0, stream>>>(W1, w1f, W2, w2f);

  // ---- CSR build ----
  hipMemsetAsync(counts, 0, (size_t)N * sizeof(int), stream);
  hipMemsetAsync(tickets, 0, 8 * sizeof(int), stream);
  hist_kernel<<<edge_blocks, 256, 0, stream>>>(dst, counts, E);
  scan_phase1<<<scan_blocks, 256, 0, stream>>>(counts, partials, N);
  scan_phase2<<<1, 1024, 0, stream>>>(partials, scan_blocks);
  scan_phase3<<<scan_blocks, 256, 0, stream>>>(counts, partials, offsets, N, E);
  fill_steal_kernel<<<1024, 256, 0, stream>>>(src, dst, offsets, counts,
                                              csr_src, tickets, E, win_size);

  // ---- layer 1 ----
  gemm_mfma<128, false><<<gemm_blocks, 256, 0, stream>>>(x, w1f, y1, N);
  agg1_kernel<<<agg_blocks, 256, 0, stream>>>(y1, csr_src, offsets, b1, h, N);

  // ---- layer 2 ----
  gemm_mfma<64, true><<<gemm_blocks, 256, 0, stream>>>(h, w2f, y2, N);
  agg2_kernel<<<agg_blocks, 256, 0, stream>>>(y2, csr_src, offsets, b2, out, N);
}

// Round 7
// 282.864 us; speedup vs baseline: 1.7116x; 1.7116x over previous
//
#include <hip/hip_runtime.h>
#include <hip/hip_bf16.h>

#define NFEAT 128
#define BCAP 8192     // bucket capacity (and bin-pass chunk size), edges
#define BSHIFT 8      // 256 nodes per bucket

typedef __attribute__((ext_vector_type(8))) short short8;
typedef __attribute__((ext_vector_type(4))) float float4v;

__device__ inline short f32_bf16(float f) {
  unsigned u = __builtin_bit_cast(unsigned, f);
  unsigned r = (u + 0x7fffu + ((u >> 16) & 1u)) >> 16;
  return (short)r;
}
__device__ inline float bf16_f32(unsigned short s) {
  return __builtin_bit_cast(float, (unsigned)s << 16);
}

// ---------------------------------------------------------------------------
// Repack W (fp32, KxCOLS row-major) into B-fragment order for
// mfma_f32_16x16x32_bf16.
// ---------------------------------------------------------------------------
__device__ inline void repack_one(const float* __restrict__ W,
                                  short* __restrict__ Wf, int COLS) {
  int nfrag = (COLS / 16) * 4 * 64;
  for (int f = threadIdx.x; f < nfrag; f += 256) {
    int lane = f & 63, c = (f >> 6) & 3, t = f >> 8;
    int k0 = c * 32 + (lane >> 4) * 8;
    int n = t * 16 + (lane & 15);
    short8 v;
#pragma unroll
    for (int j = 0; j < 8; j++) v[j] = f32_bf16(W[(size_t)(k0 + j) * COLS + n]);
    *(short8*)&Wf[(size_t)f * 8] = v;
  }
}
__global__ __launch_bounds__(256) void repack_w_kernel(
    const float* __restrict__ W1, short* __restrict__ W1f,
    const float* __restrict__ W2, short* __restrict__ W2f) {
  if (blockIdx.x == 0) repack_one(W1, W1f, 128);
  else repack_one(W2, W2f, 64);
}

// ---------------------------------------------------------------------------
// MFMA GEMM: Y_bf16[nrows x COLS] = A[nrows x 128] @ W[128 x COLS]
// ---------------------------------------------------------------------------
template <int COLS, bool IN_BF16>
__global__ __launch_bounds__(256) void gemm_mfma(
    const void* __restrict__ Av, const short* __restrict__ Wf,
    short* __restrict__ Y, int nrows) {
  constexpr int NT = COLS / 16;
  __shared__ __align__(16) short lds[COLS * 128];

  {
    const int4* s = (const int4*)Wf;
    int4* d = (int4*)lds;
    for (int i = threadIdx.x; i < COLS * 16; i += 256) d[i] = s[i];
  }
  __syncthreads();

  const int wave = threadIdx.x >> 6;
  const int lane = threadIdx.x & 63;
  const int m = lane & 15;
  const int q = lane >> 4;
  const int rowA = blockIdx.x * 64 + wave * 16 + m;

  float4v acc[NT];
#pragma unroll
  for (int t = 0; t < NT; t++) acc[t] = (float4v){0.f, 0.f, 0.f, 0.f};

  const short8* ldsf = (const short8*)lds;
#pragma unroll
  for (int c = 0; c < 4; c++) {
    short8 a = (short8){0, 0, 0, 0, 0, 0, 0, 0};
    if (rowA < nrows) {
      if constexpr (IN_BF16) {
        a = *(const short8*)((const short*)Av + (size_t)rowA * 128 + c * 32 + q * 8);
      } else {
        const float* xp = (const float*)Av + (size_t)rowA * 128 + c * 32 + q * 8;
        float4 x0 = *(const float4*)xp;
        float4 x1 = *(const float4*)(xp + 4);
        a[0] = f32_bf16(x0.x); a[1] = f32_bf16(x0.y);
        a[2] = f32_bf16(x0.z); a[3] = f32_bf16(x0.w);
        a[4] = f32_bf16(x1.x); a[5] = f32_bf16(x1.y);
        a[6] = f32_bf16(x1.z); a[7] = f32_bf16(x1.w);
      }
    }
#pragma unroll
    for (int t = 0; t < NT; t++) {
      acc[t] = __builtin_amdgcn_mfma_f32_16x16x32_bf16(
          a, ldsf[(t * 4 + c) * 64 + lane], acc[t], 0, 0, 0);
    }
  }

  const int rbase = blockIdx.x * 64 + wave * 16 + q * 4;
#pragma unroll
  for (int t = 0; t < NT; t++) {
#pragma unroll
    for (int r = 0; r < 4; r++) {
      int rr = rbase + r;
      if (rr < nrows) Y[(size_t)rr * COLS + t * 16 + m] = f32_bf16(acc[t][r]);
    }
  }
}

// ---------------------------------------------------------------------------
// Pass A: bin edges by dst bucket (256 nodes per bucket).
// Each block: LDS histogram of its 8192-edge chunk, one global bump-reserve
// per non-empty bucket, then write packed (src<<8 | dst_local) into the
// bucket's fixed-capacity region. Same-bucket writes from one block are
// CONSECUTIVE -> temporally+spatially dense, low write amplification.
// ---------------------------------------------------------------------------
__global__ __launch_bounds__(256) void bin_kernel(
    const int* __restrict__ src, const int* __restrict__ dst,
    int* __restrict__ bucket_cnt, int* __restrict__ bucket_arr,
    int E, int NB) {
  __shared__ int hist[512];
  __shared__ int cur[512];
  const int tid = threadIdx.x;
  const int base = blockIdx.x * BCAP;
  const int end = min(E, base + BCAP);
  for (int i = tid; i < NB; i += 256) hist[i] = 0;
  __syncthreads();
  for (int e = base + tid; e < end; e += 256)
    atomicAdd(&hist[dst[e] >> BSHIFT], 1);
  __syncthreads();
  for (int b = tid; b < NB; b += 256) {
    int c = hist[b];
    cur[b] = c ? (b * BCAP + atomicAdd(&bucket_cnt[b], c)) : 0;
  }
  __syncthreads();
  for (int e = base + tid; e < end; e += 256) {
    int d = dst[e];
    int b = d >> BSHIFT;
    int pos = atomicAdd(&cur[b], 1);
    bucket_arr[pos] = (src[e] << BSHIFT) | (d & 255);
  }
}

// Tiny exclusive scan over NB bucket counts (NB <= 512), plus offsets[N]=E.
__global__ __launch_bounds__(512) void bucket_scan_kernel(
    const int* __restrict__ bucket_cnt, int* __restrict__ bucket_base,
    int* __restrict__ offsets, int NB, int N, int E) {
  __shared__ int sh[512];
  const int t = threadIdx.x;
  int v = (t < NB) ? bucket_cnt[t] : 0;
  sh[t] = v;
  __syncthreads();
  for (int off = 1; off < 512; off <<= 1) {
    int o = (t >= off) ? sh[t - off] : 0;
    __syncthreads();
    sh[t] += o;
    __syncthreads();
  }
  if (t < NB) bucket_base[t] = sh[t] - v;  // exclusive
  if (t == 0) offsets[N] = E;
}

// ---------------------------------------------------------------------------
// Pass B: one block per bucket. Load bucket edges to LDS, 256-counter
// histogram + scan + scatter in LDS, write csr segment + offsets coalesced.
// ---------------------------------------------------------------------------
__global__ __launch_bounds__(256) void csr_build_kernel(
    const int* __restrict__ bucket_arr, const int* __restrict__ bucket_cnt,
    const int* __restrict__ bucket_base, int* __restrict__ offsets,
    int* __restrict__ csr_src, int N) {
  __shared__ int eds[BCAP];
  __shared__ int stage[BCAP];
  __shared__ int cnt256[256], pfx[256], cur[256];
  const int b = blockIdx.x;
  const int tid = threadIdx.x;
  const int cnt = bucket_cnt[b];
  const int gbase = bucket_base[b];
  const int node0 = b << BSHIFT;
  const int nnodes = min(256, N - node0);

  for (int i = tid; i < cnt; i += 256) eds[i] = bucket_arr[b * BCAP + i];
  cnt256[tid] = 0;
  __syncthreads();
  for (int i = tid; i < cnt; i += 256) atomicAdd(&cnt256[eds[i] & 255], 1);
  __syncthreads();
  int v = cnt256[tid];
  pfx[tid] = v;
  __syncthreads();
  for (int off = 1; off < 256; off <<= 1) {
    int o = (tid >= off) ? pfx[tid - off] : 0;
    __syncthreads();
    pfx[tid] += o;
    __syncthreads();
  }
  int excl = pfx[tid] - v;
  cur[tid] = excl;
  if (tid < nnodes) offsets[node0 + tid] = gbase + excl;
  __syncthreads();
  for (int i = tid; i < cnt; i += 256) {
    int e = eds[i];
    int pos = atomicAdd(&cur[e & 255], 1);
    stage[pos] = e >> BSHIFT;
  }
  __syncthreads();
  for (int i = tid; i < cnt; i += 256) csr_src[gbase + i] = stage[i];
}

// ---------------------------------------------------------------------------
// Aggregations (one wave per node, fp32 accumulate, 4-way unrolled gather)
// ---------------------------------------------------------------------------
__global__ __launch_bounds__(256) void agg1_kernel(
    const short* __restrict__ Y, const int* __restrict__ csr_src,
    const int* __restrict__ offsets, const float* __restrict__ bias,
    short* __restrict__ H, int N) {
  const int node = (blockIdx.x * 256 + threadIdx.x) >> 6;
  const int lane = threadIdx.x & 63;
  if (node >= N) return;
  const int start = offsets[node];
  const int end = offsets[node + 1];
  float a0 = bias[2 * lane], a1 = bias[2 * lane + 1];
  for (int base = start; base < end; base += 64) {
    int my = (base + lane < end) ? csr_src[base + lane] : 0;
    int mcnt = min(64, end - base);
    int j = 0;
    for (; j + 4 <= mcnt; j += 4) {
      int s0 = __shfl(my, j + 0);
      int s1 = __shfl(my, j + 1);
      int s2 = __shfl(my, j + 2);
      int s3 = __shfl(my, j + 3);
      unsigned v0 = *(const unsigned*)&Y[(size_t)s0 * 128 + 2 * lane];
      unsigned v1 = *(const unsigned*)&Y[(size_t)s1 * 128 + 2 * lane];
      unsigned v2 = *(const unsigned*)&Y[(size_t)s2 * 128 + 2 * lane];
      unsigned v3 = *(const unsigned*)&Y[(size_t)s3 * 128 + 2 * lane];
      a0 += __builtin_bit_cast(float, v0 << 16);
      a1 += __builtin_bit_cast(float, v0 & 0xffff0000u);
      a0 += __builtin_bit_cast(float, v1 << 16);
      a1 += __builtin_bit_cast(float, v1 & 0xffff0000u);
      a0 += __builtin_bit_cast(float, v2 << 16);
      a1 += __builtin_bit_cast(float, v2 & 0xffff0000u);
      a0 += __builtin_bit_cast(float, v3 << 16);
      a1 += __builtin_bit_cast(float, v3 & 0xffff0000u);
    }
    for (; j < mcnt; j++) {
      int s = __shfl(my, j);
      unsigned v = *(const unsigned*)&Y[(size_t)s * 128 + 2 * lane];
      a0 += __builtin_bit_cast(float, v << 16);
      a1 += __builtin_bit_cast(float, v & 0xffff0000u);
    }
  }
  a0 = fmaxf(a0, 0.f);
  a1 = fmaxf(a1, 0.f);
  unsigned outv = (unsigned)(unsigned short)f32_bf16(a0) |
                  ((unsigned)(unsigned short)f32_bf16(a1) << 16);
  *(unsigned*)&H[(size_t)node * 128 + 2 * lane] = outv;
}

__global__ __launch_bounds__(256) void agg2_kernel(
    const short* __restrict__ Y, const int* __restrict__ csr_src,
    const int* __restrict__ offsets, const float* __restrict__ bias,
    float* __restrict__ out, int N) {
  const int node = (blockIdx.x * 256 + threadIdx.x) >> 6;
  const int lane = threadIdx.x & 63;
  if (node >= N) return;
  const int start = offsets[node];
  const int end = offsets[node + 1];
  float acc = bias[lane];
  for (int base = start; base < end; base += 64) {
    int my = (base + lane < end) ? csr_src[base + lane] : 0;
    int mcnt = min(64, end - base);
    int j = 0;
    for (; j + 4 <= mcnt; j += 4) {
      int s0 = __shfl(my, j + 0);
      int s1 = __shfl(my, j + 1);
      int s2 = __shfl(my, j + 2);
      int s3 = __shfl(my, j + 3);
      unsigned short w0 = *(const unsigned short*)&Y[(size_t)s0 * 64 + lane];
      unsigned short w1 = *(const unsigned short*)&Y[(size_t)s1 * 64 + lane];
      unsigned short w2 = *(const unsigned short*)&Y[(size_t)s2 * 64 + lane];
      unsigned short w3 = *(const unsigned short*)&Y[(size_t)s3 * 64 + lane];
      acc += bf16_f32(w0) + bf16_f32(w1) + bf16_f32(w2) + bf16_f32(w3);
    }
    for (; j < mcnt; j++) {
      int s = __shfl(my, j);
      acc += bf16_f32(*(const unsigned short*)&Y[(size_t)s * 64 + lane]);
    }
  }
  out[(size_t)node * 64 + lane] = acc;
}

extern "C" void kernel_launch(void* const* d_in, const int* in_sizes, int n_in,
                              void* d_out, int out_size, void* d_ws, size_t ws_size,
                              hipStream_t stream) {
  const float* x  = (const float*)d_in[0];
  const int* src  = (const int*)d_in[1];
  const int* dst  = (const int*)d_in[2];
  const float* W1 = (const float*)d_in[3];
  const float* b1 = (const float*)d_in[4];
  const float* W2 = (const float*)d_in[5];
  const float* b2 = (const float*)d_in[6];
  float* out = (float*)d_out;

  const int N = in_sizes[0] / NFEAT;   // 100000
  const int E = in_sizes[1];           // 1600000
  const int NB = (N + 255) >> BSHIFT;  // 391 buckets

  // workspace layout
  short* y1  = (short*)d_ws;                       // N*128 bf16
  short* h   = y1 + (size_t)N * 128;               // N*128 bf16
  short* y2  = h + (size_t)N * 128;                // N*64 bf16
  short* w1f = y2 + (size_t)N * 64;                // 128*128 bf16
  short* w2f = w1f + 128 * 128;                    // 128*64 bf16
  int* bucket_cnt  = (int*)(((uintptr_t)(w2f + 128 * 64) + 15) & ~(uintptr_t)15);
  int* bucket_base = bucket_cnt + 512;             // 512
  int* offsets     = bucket_base + 512;            // N+1
  int* csr_src     = offsets + N + 1;              // E
  int* bucket_arr  = csr_src + E;                  // NB*BCAP

  const int gemm_blocks = (N + 63) / 64;
  const int agg_blocks = (N * 64 + 255) / 256;
  const int bin_blocks = (E + BCAP - 1) / BCAP;

  // ---- weight repack ----
  repack_w_kernel<<<2, 256, 0, stream>>>(W1, w1f, W2, w2f);

  // ---- CSR build via LDS-staged bucket sort ----
  hipMemsetAsync(bucket_cnt, 0, 512 * sizeof(int), stream);
  bin_kernel<<<bin_blocks, 256, 0, stream>>>(src, dst, bucket_cnt, bucket_arr,
                                             E, NB);
  bucket_scan_kernel<<<1, 512, 0, stream>>>(bucket_cnt, bucket_base, offsets,
                                            NB, N, E);
  csr_build_kernel<<<NB, 256, 0, stream>>>(bucket_arr, bucket_cnt, bucket_base,
                                           offsets, csr_src, N);

  // ---- layer 1 ----
  gemm_mfma<128, false><<<gemm_blocks, 256, 0, stream>>>(x, w1f, y1, N);
  agg1_kernel<<<agg_blocks, 256, 0, stream>>>(y1, csr_src, offsets, b1, h, N);

  // ---- layer 2 ----
  gemm_mfma<64, true><<<gemm_blocks, 256, 0, stream>>>(h, w2f, y2, N);
  agg2_kernel<<<agg_blocks, 256, 0, stream>>>(y2, csr_src, offsets, b2, out, N);
}

// Round 8
// 274.577 us; speedup vs baseline: 1.7633x; 1.0302x over previous
//
#include <hip/hip_runtime.h>
#include <hip/hip_bf16.h>

#define NFEAT 128
#define BCAP 8192     // bucket capacity (and bin-pass chunk size), edges
#define BSHIFT 8      // 256 nodes per bucket

typedef __attribute__((ext_vector_type(8))) short short8;
typedef __attribute__((ext_vector_type(4))) float float4v;

__device__ inline short f32_bf16(float f) {
  unsigned u = __builtin_bit_cast(unsigned, f);
  unsigned r = (u + 0x7fffu + ((u >> 16) & 1u)) >> 16;
  return (short)r;
}
__device__ inline float bf16_f32(unsigned short s) {
  return __builtin_bit_cast(float, (unsigned)s << 16);
}

// ---------------------------------------------------------------------------
// Repack W (fp32, KxCOLS row-major) into B-fragment order for
// mfma_f32_16x16x32_bf16.
// ---------------------------------------------------------------------------
__device__ inline void repack_one(const float* __restrict__ W,
                                  short* __restrict__ Wf, int COLS) {
  int nfrag = (COLS / 16) * 4 * 64;
  for (int f = threadIdx.x; f < nfrag; f += 256) {
    int lane = f & 63, c = (f >> 6) & 3, t = f >> 8;
    int k0 = c * 32 + (lane >> 4) * 8;
    int n = t * 16 + (lane & 15);
    short8 v;
#pragma unroll
    for (int j = 0; j < 8; j++) v[j] = f32_bf16(W[(size_t)(k0 + j) * COLS + n]);
    *(short8*)&Wf[(size_t)f * 8] = v;
  }
}
__global__ __launch_bounds__(256) void repack_w_kernel(
    const float* __restrict__ W1, short* __restrict__ W1f,
    const float* __restrict__ W2, short* __restrict__ W2f) {
  if (blockIdx.x == 0) repack_one(W1, W1f, 128);
  else repack_one(W2, W2f, 64);
}

// ---------------------------------------------------------------------------
// GEMM device role: Y_bf16[nrows x COLS] = A[nrows x 128] @ W[128 x COLS]
// ---------------------------------------------------------------------------
template <int COLS, bool IN_BF16>
__device__ inline void gemm_role(int bid, const void* __restrict__ Av,
                                 const short* __restrict__ Wf,
                                 short* __restrict__ Y, int nrows,
                                 short* lds) {
  constexpr int NT = COLS / 16;
  {
    const int4* s = (const int4*)Wf;
    int4* d = (int4*)lds;
    for (int i = threadIdx.x; i < COLS * 16; i += 256) d[i] = s[i];
  }
  __syncthreads();

  const int wave = threadIdx.x >> 6;
  const int lane = threadIdx.x & 63;
  const int m = lane & 15;
  const int q = lane >> 4;
  const int rowA = bid * 64 + wave * 16 + m;

  float4v acc[NT];
#pragma unroll
  for (int t = 0; t < NT; t++) acc[t] = (float4v){0.f, 0.f, 0.f, 0.f};

  const short8* ldsf = (const short8*)lds;
#pragma unroll
  for (int c = 0; c < 4; c++) {
    short8 a = (short8){0, 0, 0, 0, 0, 0, 0, 0};
    if (rowA < nrows) {
      if constexpr (IN_BF16) {
        a = *(const short8*)((const short*)Av + (size_t)rowA * 128 + c * 32 + q * 8);
      } else {
        const float* xp = (const float*)Av + (size_t)rowA * 128 + c * 32 + q * 8;
        float4 x0 = *(const float4*)xp;
        float4 x1 = *(const float4*)(xp + 4);
        a[0] = f32_bf16(x0.x); a[1] = f32_bf16(x0.y);
        a[2] = f32_bf16(x0.z); a[3] = f32_bf16(x0.w);
        a[4] = f32_bf16(x1.x); a[5] = f32_bf16(x1.y);
        a[6] = f32_bf16(x1.z); a[7] = f32_bf16(x1.w);
      }
    }
#pragma unroll
    for (int t = 0; t < NT; t++) {
      acc[t] = __builtin_amdgcn_mfma_f32_16x16x32_bf16(
          a, ldsf[(t * 4 + c) * 64 + lane], acc[t], 0, 0, 0);
    }
  }

  const int rbase = bid * 64 + wave * 16 + q * 4;
#pragma unroll
  for (int t = 0; t < NT; t++) {
#pragma unroll
    for (int r = 0; r < 4; r++) {
      int rr = rbase + r;
      if (rr < nrows) Y[(size_t)rr * COLS + t * 16 + m] = f32_bf16(acc[t][r]);
    }
  }
}

// standalone gemm kernel (layer 2)
template <int COLS, bool IN_BF16>
__global__ __launch_bounds__(256) void gemm_mfma(
    const void* __restrict__ Av, const short* __restrict__ Wf,
    short* __restrict__ Y, int nrows) {
  __shared__ __align__(16) short lds[COLS * 128];
  gemm_role<COLS, IN_BF16>(blockIdx.x, Av, Wf, Y, nrows, lds);
}

// ---------------------------------------------------------------------------
// Bin device role: LDS histogram of an 8192-edge chunk, bump-reserve per
// bucket, write packed (src<<8 | dst_local) into bucket regions.
// ---------------------------------------------------------------------------
__device__ inline void bin_role(int bid, const int* __restrict__ src,
                                const int* __restrict__ dst,
                                int* __restrict__ bucket_cnt,
                                int* __restrict__ bucket_arr, int E, int NB,
                                int* hist, int* cur) {
  const int tid = threadIdx.x;
  const int base = bid * BCAP;
  const int end = min(E, base + BCAP);
  for (int i = tid; i < NB; i += 256) hist[i] = 0;
  __syncthreads();
  for (int e = base + tid; e < end; e += 256)
    atomicAdd(&hist[dst[e] >> BSHIFT], 1);
  __syncthreads();
  for (int b = tid; b < NB; b += 256) {
    int c = hist[b];
    cur[b] = c ? (b * BCAP + atomicAdd(&bucket_cnt[b], c)) : 0;
  }
  __syncthreads();
  for (int e = base + tid; e < end; e += 256) {
    int d = dst[e];
    int b = d >> BSHIFT;
    int pos = atomicAdd(&cur[b], 1);
    bucket_arr[pos] = (src[e] << BSHIFT) | (d & 255);
  }
}

// ---------------------------------------------------------------------------
// K1: fused gemm1 + bin. Disjoint inputs, union LDS (32 KB).
// ---------------------------------------------------------------------------
__global__ __launch_bounds__(256) void k1_gemm_bin(
    const float* __restrict__ x, const short* __restrict__ w1f,
    short* __restrict__ y1, int nrows, int ngemm,
    const int* __restrict__ src, const int* __restrict__ dst,
    int* __restrict__ bucket_cnt, int* __restrict__ bucket_arr,
    int E, int NB) {
  __shared__ __align__(16) char smem[128 * 128 * 2];  // 32 KB union
  if ((int)blockIdx.x < ngemm) {
    gemm_role<128, false>(blockIdx.x, x, w1f, y1, nrows, (short*)smem);
  } else {
    int* h = (int*)smem;
    bin_role(blockIdx.x - ngemm, src, dst, bucket_cnt, bucket_arr, E, NB,
             h, h + 512);
  }
}

// Tiny exclusive scan over NB bucket counts (NB <= 512), plus offsets[N]=E.
__global__ __launch_bounds__(512) void bucket_scan_kernel(
    const int* __restrict__ bucket_cnt, int* __restrict__ bucket_base,
    int* __restrict__ offsets, int NB, int N, int E) {
  __shared__ int sh[512];
  const int t = threadIdx.x;
  int v = (t < NB) ? bucket_cnt[t] : 0;
  sh[t] = v;
  __syncthreads();
  for (int off = 1; off < 512; off <<= 1) {
    int o = (t >= off) ? sh[t - off] : 0;
    __syncthreads();
    sh[t] += o;
    __syncthreads();
  }
  if (t < NB) bucket_base[t] = sh[t] - v;  // exclusive
  if (t == 0) offsets[N] = E;
}

// ---------------------------------------------------------------------------
// One block per bucket: LDS counting sort -> coalesced csr_src + offsets.
// ---------------------------------------------------------------------------
__global__ __launch_bounds__(256) void csr_build_kernel(
    const int* __restrict__ bucket_arr, const int* __restrict__ bucket_cnt,
    const int* __restrict__ bucket_base, int* __restrict__ offsets,
    int* __restrict__ csr_src, int N) {
  __shared__ int eds[BCAP];
  __shared__ int stage[BCAP];
  __shared__ int cnt256[256], pfx[256], cur[256];
  const int b = blockIdx.x;
  const int tid = threadIdx.x;
  const int cnt = bucket_cnt[b];
  const int gbase = bucket_base[b];
  const int node0 = b << BSHIFT;
  const int nnodes = min(256, N - node0);

  for (int i = tid; i < cnt; i += 256) eds[i] = bucket_arr[b * BCAP + i];
  cnt256[tid] = 0;
  __syncthreads();
  for (int i = tid; i < cnt; i += 256) atomicAdd(&cnt256[eds[i] & 255], 1);
  __syncthreads();
  int v = cnt256[tid];
  pfx[tid] = v;
  __syncthreads();
  for (int off = 1; off < 256; off <<= 1) {
    int o = (tid >= off) ? pfx[tid - off] : 0;
    __syncthreads();
    pfx[tid] += o;
    __syncthreads();
  }
  int excl = pfx[tid] - v;
  cur[tid] = excl;
  if (tid < nnodes) offsets[node0 + tid] = gbase + excl;
  __syncthreads();
  for (int i = tid; i < cnt; i += 256) {
    int e = eds[i];
    int pos = atomicAdd(&cur[e & 255], 1);
    stage[pos] = e >> BSHIFT;
  }
  __syncthreads();
  for (int i = tid; i < cnt; i += 256) csr_src[gbase + i] = stage[i];
}

// ---------------------------------------------------------------------------
// Aggregations (one wave per node, fp32 accumulate, 8-way unrolled gather)
// ---------------------------------------------------------------------------
__global__ __launch_bounds__(256) void agg1_kernel(
    const short* __restrict__ Y, const int* __restrict__ csr_src,
    const int* __restrict__ offsets, const float* __restrict__ bias,
    short* __restrict__ H, int N) {
  const int node = (blockIdx.x * 256 + threadIdx.x) >> 6;
  const int lane = threadIdx.x & 63;
  if (node >= N) return;
  const int start = offsets[node];
  const int end = offsets[node + 1];
  float a0 = bias[2 * lane], a1 = bias[2 * lane + 1];
  for (int base = start; base < end; base += 64) {
    int my = (base + lane < end) ? csr_src[base + lane] : 0;
    int mcnt = min(64, end - base);
    int j = 0;
    for (; j + 8 <= mcnt; j += 8) {
      unsigned v[8];
#pragma unroll
      for (int k = 0; k < 8; k++) {
        int s = __shfl(my, j + k);
        v[k] = *(const unsigned*)&Y[(size_t)s * 128 + 2 * lane];
      }
#pragma unroll
      for (int k = 0; k < 8; k++) {
        a0 += __builtin_bit_cast(float, v[k] << 16);
        a1 += __builtin_bit_cast(float, v[k] & 0xffff0000u);
      }
    }
    for (; j + 4 <= mcnt; j += 4) {
      unsigned v[4];
#pragma unroll
      for (int k = 0; k < 4; k++) {
        int s = __shfl(my, j + k);
        v[k] = *(const unsigned*)&Y[(size_t)s * 128 + 2 * lane];
      }
#pragma unroll
      for (int k = 0; k < 4; k++) {
        a0 += __builtin_bit_cast(float, v[k] << 16);
        a1 += __builtin_bit_cast(float, v[k] & 0xffff0000u);
      }
    }
    for (; j < mcnt; j++) {
      int s = __shfl(my, j);
      unsigned v = *(const unsigned*)&Y[(size_t)s * 128 + 2 * lane];
      a0 += __builtin_bit_cast(float, v << 16);
      a1 += __builtin_bit_cast(float, v & 0xffff0000u);
    }
  }
  a0 = fmaxf(a0, 0.f);
  a1 = fmaxf(a1, 0.f);
  unsigned outv = (unsigned)(unsigned short)f32_bf16(a0) |
                  ((unsigned)(unsigned short)f32_bf16(a1) << 16);
  *(unsigned*)&H[(size_t)node * 128 + 2 * lane] = outv;
}

__global__ __launch_bounds__(256) void agg2_kernel(
    const short* __restrict__ Y, const int* __restrict__ csr_src,
    const int* __restrict__ offsets, const float* __restrict__ bias,
    float* __restrict__ out, int N) {
  const int node = (blockIdx.x * 256 + threadIdx.x) >> 6;
  const int lane = threadIdx.x & 63;
  if (node >= N) return;
  const int start = offsets[node];
  const int end = offsets[node + 1];
  float acc = bias[lane];
  for (int base = start; base < end; base += 64) {
    int my = (base + lane < end) ? csr_src[base + lane] : 0;
    int mcnt = min(64, end - base);
    int j = 0;
    for (; j + 8 <= mcnt; j += 8) {
      unsigned short w[8];
#pragma unroll
      for (int k = 0; k < 8; k++) {
        int s = __shfl(my, j + k);
        w[k] = *(const unsigned short*)&Y[(size_t)s * 64 + lane];
      }
#pragma unroll
      for (int k = 0; k < 8; k++) acc += bf16_f32(w[k]);
    }
    for (; j + 4 <= mcnt; j += 4) {
      unsigned short w[4];
#pragma unroll
      for (int k = 0; k < 4; k++) {
        int s = __shfl(my, j + k);
        w[k] = *(const unsigned short*)&Y[(size_t)s * 64 + lane];
      }
#pragma unroll
      for (int k = 0; k < 4; k++) acc += bf16_f32(w[k]);
    }
    for (; j < mcnt; j++) {
      int s = __shfl(my, j);
      acc += bf16_f32(*(const unsigned short*)&Y[(size_t)s * 64 + lane]);
    }
  }
  out[(size_t)node * 64 + lane] = acc;
}

extern "C" void kernel_launch(void* const* d_in, const int* in_sizes, int n_in,
                              void* d_out, int out_size, void* d_ws, size_t ws_size,
                              hipStream_t stream) {
  const float* x  = (const float*)d_in[0];
  const int* src  = (const int*)d_in[1];
  const int* dst  = (const int*)d_in[2];
  const float* W1 = (const float*)d_in[3];
  const float* b1 = (const float*)d_in[4];
  const float* W2 = (const float*)d_in[5];
  const float* b2 = (const float*)d_in[6];
  float* out = (float*)d_out;

  const int N = in_sizes[0] / NFEAT;   // 100000
  const int E = in_sizes[1];           // 1600000
  const int NB = (N + 255) >> BSHIFT;  // 391 buckets

  // workspace layout
  short* y1  = (short*)d_ws;                       // N*128 bf16
  short* h   = y1 + (size_t)N * 128;               // N*128 bf16
  short* y2  = h + (size_t)N * 128;                // N*64 bf16
  short* w1f = y2 + (size_t)N * 64;                // 128*128 bf16
  short* w2f = w1f + 128 * 128;                    // 128*64 bf16
  int* bucket_cnt  = (int*)(((uintptr_t)(w2f + 128 * 64) + 15) & ~(uintptr_t)15);
  int* bucket_base = bucket_cnt + 512;             // 512
  int* offsets     = bucket_base + 512;            // N+1
  int* csr_src     = offsets + N + 1;              // E
  int* bucket_arr  = csr_src + E;                  // NB*BCAP

  const int gemm_blocks = (N + 63) / 64;
  const int agg_blocks = (N * 64 + 255) / 256;
  const int bin_blocks = (E + BCAP - 1) / BCAP;

  // ---- weight repack (must finish before K1 reads w1f) ----
  repack_w_kernel<<<2, 256, 0, stream>>>(W1, w1f, W2, w2f);
  hipMemsetAsync(bucket_cnt, 0, 512 * sizeof(int), stream);

  // ---- K1: gemm1 fused with bin ----
  k1_gemm_bin<<<gemm_blocks + bin_blocks, 256, 0, stream>>>(
      x, w1f, y1, N, gemm_blocks, src, dst, bucket_cnt, bucket_arr, E, NB);

  // ---- CSR finalize ----
  bucket_scan_kernel<<<1, 512, 0, stream>>>(bucket_cnt, bucket_base, offsets,
                                            NB, N, E);
  csr_build_kernel<<<NB, 256, 0, stream>>>(bucket_arr, bucket_cnt, bucket_base,
                                           offsets, csr_src, N);

  // ---- layer 1 aggregation ----
  agg1_kernel<<<agg_blocks, 256, 0, stream>>>(y1, csr_src, offsets, b1, h, N);

  // ---- layer 2 ----
  gemm_mfma<64, true><<<gemm_blocks, 256, 0, stream>>>(h, w2f, y2, N);
  agg2_kernel<<<agg_blocks, 256, 0, stream>>>(y2, csr_src, offsets, b2, out, N);
}